// Round 8
// baseline (96.393 us; speedup 1.0000x reference)
//
#include <hip/hip_runtime.h>

#define W 2048
#define H 2048
#define TX 64
#define TY 32
#define DW 92          // row stride (floats); mult of 4, 92%32=28 staggers banks
#define DH 52          // TY + 20
#define VH 36          // TY + 4
// LDS col lc <-> image col gj = j0 - 12 + lc ; Ds row li <-> image row gi = i0 - 10 + li

typedef float f4 __attribute__((ext_vector_type(4)));

// Fused guided-filter update, TWO vertically-adjacent 64x32 tiles per block.
//   D  = y - X
//   D2 = D - hsum5(vsum17(D))/Ni1
//   out= y - D2 + hsum17(vsum5(D2))/Ni2
// Both tiles' global->LDS staging issues up front: tile B's HBM latency hides
// under tile A's LDS/VALU compute. Shared Vs buffer (barrier-protected reuse).
__global__ __launch_bounds__(512, 4) void guided_fused(const float* __restrict__ X,
                                                       const float* __restrict__ y,
                                                       float* __restrict__ out) {
    __shared__ __align__(16) float DsA[DH * DW];   // 19.1 KB
    __shared__ __align__(16) float DsB[DH * DW];   // 19.1 KB
    __shared__ __align__(16) float Vs[VH * DW];    // 13.25 KB  (total 51.5 KB -> 3 blocks/CU)

    const int tid = threadIdx.x;
    const int bx = blockIdx.x, byp = blockIdx.y;
    const int j0 = bx * TX;
    const int i0A = (2 * byp) * TY;
    const int i0B = i0A + TY;
    const bool xin = (bx >= 1) & (bx <= 30);
    const bool intA = xin & (byp >= 1);                 // by=2byp: >=1 iff byp>=1; <=62 always (max 62)
    const bool intB = xin & (2 * byp + 1 <= 62);        // by=2byp+1: >=1 always
    const float R85 = 0.011764706f;                     // 1/85

    // ---- S1 (both tiles): D = y - X over 52 rows x 22 aligned f4 col-groups ----
    auto load_tile = [&](float* __restrict__ Ds, int i0, bool interior) {
        if (interior) {
            #pragma unroll
            for (int k = 0; k < 3; ++k) {
                int c = tid + k * 512;
                if (c < DH * 22) {
                    int li = c / 22, g = c - li * 22;
                    int off = (i0 - 10 + li) * W + (j0 - 12) + 4 * g;   // 16B aligned
                    f4 yv = *(const f4*)&y[off];
                    f4 xv = *(const f4*)&X[off];
                    *(f4*)&Ds[li * DW + 4 * g] = yv - xv;
                }
            }
        } else {
            #pragma unroll
            for (int k = 0; k < 3; ++k) {
                int c = tid + k * 512;
                if (c < DH * 22) {
                    int li = c / 22, g = c - li * 22;
                    int gi = i0 - 10 + li, gj = j0 - 12 + 4 * g;
                    f4 d = {0.f, 0.f, 0.f, 0.f};
                    if ((unsigned)gi < H) {
                        if (gj >= 0 && gj + 3 < W) {
                            f4 yv = *(const f4*)&y[gi * W + gj];
                            f4 xv = *(const f4*)&X[gi * W + gj];
                            d = yv - xv;
                        } else {
                            #pragma unroll
                            for (int e = 0; e < 4; ++e) {
                                int gc = gj + e;
                                if ((unsigned)gc < W) d[e] = y[gi * W + gc] - X[gi * W + gc];
                            }
                        }
                    }
                    *(f4*)&Ds[li * DW + 4 * g] = d;
                }
            }
        }
    };

    auto compute_tile = [&](float* __restrict__ Ds, int i0, bool interior) {
        // ---- S2: V1[v] = vsum17(D rows v..v+16); 198 tasks ----
        if (tid < 198) {
            int seg = tid / 22, g = tid - seg * 22;
            int v0 = seg * 4;
            const f4* dp = (const f4*)&Ds[v0 * DW + 4 * g];     // row stride 23 f4
            f4 r0 = dp[0], r1 = dp[23], r2 = dp[46];
            f4 s = r0 + r1 + r2;
            #pragma unroll
            for (int t = 3; t < 17; ++t) s += dp[t * 23];
            f4* vp = (f4*)&Vs[v0 * DW + 4 * g];
            vp[0] = s;
            s += dp[17 * 23] - r0; vp[23] = s;
            s += dp[18 * 23] - r1; vp[46] = s;
            s += dp[19 * 23] - r2; vp[69] = s;
        }
        __syncthreads();

        // ---- S3: D2 = D - hsum5(V1)/Ni1, in-place; 756 tasks ----
        #pragma unroll
        for (int k = 0; k < 2; ++k) {
            int c = tid + k * 512;
            if (c < VH * 21) {
                int v = c / 21, t = c - v * 21;
                f4 a = *(const f4*)&Vs[v * DW + 4 * t];
                f4 b = *(const f4*)&Vs[v * DW + 4 * t + 4];
                float m = a.y + a.z + a.w + b.x;
                float s0 = m + a.x;
                float s1 = m + b.y;
                float s2 = a.z + a.w + b.x + b.y + b.z;
                float s3 = a.w + b.x + b.y + b.z + b.w;
                int off = (v + 8) * DW + 4 * t + 2;
                if (interior) {
                    Ds[off + 0] -= s0 * R85;
                    Ds[off + 1] -= s1 * R85;
                    Ds[off + 2] -= s2 * R85;
                    Ds[off + 3] -= s3 * R85;
                } else {
                    int gi = i0 + v - 2;
                    if ((unsigned)gi < H) {
                        int r0c = gi - 8 > 0 ? gi - 8 : 0;
                        int r1c = gi + 8 < H - 1 ? gi + 8 : H - 1;
                        float rowsN = (float)(r1c - r0c + 1);
                        float corr[4] = {s0, s1, s2, s3};
                        #pragma unroll
                        for (int e = 0; e < 4; ++e) {
                            int gj = j0 - 10 + 4 * t + e;
                            if ((unsigned)gj < W) {
                                int c0 = gj - 2 > 0 ? gj - 2 : 0;
                                int c1 = gj + 2 < W - 1 ? gj + 2 : W - 1;
                                corr[e] *= __builtin_amdgcn_rcpf(rowsN * (float)(c1 - c0 + 1));
                            } else {
                                corr[e] = 0.f;      // keep zero-padding
                            }
                            Ds[off + e] -= corr[e];
                        }
                    }
                }
            }
        }
        __syncthreads();

        // ---- S4: V2[w] = vsum5(D2 rows w+8..w+12); 320 tasks ----
        if (tid < 320) {
            int seg = tid / 20, g = tid - seg * 20;
            int w0 = seg * 2;
            int lc = 4 * g + 4;
            const f4* dp = (const f4*)&Ds[(w0 + 8) * DW + lc];   // aligned b128
            f4 r0 = dp[0];
            f4 s = r0 + dp[23] + dp[46] + dp[69] + dp[92];
            f4* vp = (f4*)&Vs[w0 * DW + lc];
            vp[0] = s;
            s += dp[115] - r0; vp[23] = s;
        }
        __syncthreads();

        // ---- S5: out = y - D2 + hsum17(V2)/Ni2; 512 tasks ----
        {
            int w = tid >> 4, x0 = (tid & 15) * 4;
            int gbase = (i0 + w) * W + j0 + x0;
            f4 yv = *(const f4*)&y[gbase];                       // issue global read early
            float val[20];
            const f4* vp = (const f4*)&Vs[w * DW + x0 + 4];
            #pragma unroll
            for (int q = 0; q < 5; ++q) {
                f4 tq = vp[q];
                val[q * 4 + 0] = tq.x; val[q * 4 + 1] = tq.y;
                val[q * 4 + 2] = tq.z; val[q * 4 + 3] = tq.w;
            }
            float s = 0.f;
            #pragma unroll
            for (int c = 0; c < 17; ++c) s += val[c];
            f4 d2 = *(const f4*)&Ds[(w + 10) * DW + x0 + 12];    // aligned b128
            f4 o;
            if (interior) {
                o.x = yv.x - d2.x + s * R85;
                s += val[17] - val[0];
                o.y = yv.y - d2.y + s * R85;
                s += val[18] - val[1];
                o.z = yv.z - d2.z + s * R85;
                s += val[19] - val[2];
                o.w = yv.w - d2.w + s * R85;
            } else {
                int gi = i0 + w;
                int r0c = gi - 2 > 0 ? gi - 2 : 0;
                int r1c = gi + 2 < H - 1 ? gi + 2 : H - 1;
                float rowsN = (float)(r1c - r0c + 1);
                float res[4];
                #pragma unroll
                for (int e = 0; e < 4; ++e) {
                    int gj = j0 + x0 + e;
                    int c0 = gj - 8 > 0 ? gj - 8 : 0;
                    int c1 = gj + 8 < W - 1 ? gj + 8 : W - 1;
                    res[e] = s * __builtin_amdgcn_rcpf(rowsN * (float)(c1 - c0 + 1));
                    if (e < 3) s += val[e + 17] - val[e];
                }
                o.x = yv.x - d2.x + res[0];
                o.y = yv.y - d2.y + res[1];
                o.z = yv.z - d2.z + res[2];
                o.w = yv.w - d2.w + res[3];
            }
            *(f4*)&out[gbase] = o;
        }
    };

    // Stage BOTH tiles first: tile B's HBM latency hides under tile A's compute.
    load_tile(DsA, i0A, intA);
    load_tile(DsB, i0B, intB);
    __syncthreads();

    compute_tile(DsA, i0A, intA);
    __syncthreads();            // protect shared Vs: S5(A) readers vs S2(B) writers
    compute_tile(DsB, i0B, intB);
}

extern "C" void kernel_launch(void* const* d_in, const int* in_sizes, int n_in,
                              void* d_out, int out_size, void* d_ws, size_t ws_size,
                              hipStream_t stream) {
    const float* X = (const float*)d_in[0];
    const float* y = (const float*)d_in[1];
    float* out = (float*)d_out;

    dim3 blk(512, 1, 1);
    dim3 grd(W / TX, H / (2 * TY), 1);   // 32 x 32 = 1024 tile-pair blocks
    guided_fused<<<grd, blk, 0, stream>>>(X, y, out);
}

// Round 9
// 90.599 us; speedup vs baseline: 1.0640x; 1.0640x over previous
//
#include <hip/hip_runtime.h>

#define W 2048
#define H 2048
#define TX 64
#define TY 32
#define DW 92          // Ds row stride (floats); 92%32=28 staggers banks; f4 row stride 23
#define DH 52          // TY + 20
#define HS 88          // Hs row stride; 88%32=24
// Ds col lc <-> img col gj = j0 - 12 + lc (lc 0..87); Ds row li <-> img row gi = i0 - 10 + li
// Hs (pass1): H[r][hl] = hsum5(D[r]) centered at img col j0 - 8 + hl (hl 0..79)
// Hs (pass2, reused): V2[w][vl] = vsum5(D2) at img col j0 - 8 + vl, out row i0 + w

typedef float f4 __attribute__((ext_vector_type(4)));

// Fused guided-filter update:
//   D  = y - X
//   D2 = D - vsum17(hsum5(D))/Ni1          (pass 1, hsum-first: cheaper LDS)
//   out= y - D2 + hsum17(vsum5(D2))/Ni2    (pass 2, vsum-first: shrink rows before 17-tap)
// Interior blocks (90.8%): Ni1 = Ni2 = 85.
__global__ __launch_bounds__(512, 8) void guided_fused(const float* __restrict__ X,
                                                       const float* __restrict__ y,
                                                       float* __restrict__ out) {
    __shared__ __align__(16) float Ds[DH * DW];   // 19.1 KB: D, then D2 in-place (rows 8..43)
    __shared__ __align__(16) float Hs[DH * HS];   // 18.3 KB: H (pass1), then V2 (pass2)

    const int tid = threadIdx.x;
    const int bx = blockIdx.x, by = blockIdx.y;
    const int i0 = by * TY, j0 = bx * TX;
    const bool interior = (bx >= 1) & (bx <= 30) & (by >= 1) & (by <= 62);
    const float R85 = 0.011764706f;               // 1/85

    // ---- S1: D = y - X over 52 rows x 22 aligned f4 col-groups (lc = 4g, gj = j0-12+4g) ----
    if (interior) {
        #pragma unroll
        for (int k = 0; k < 3; ++k) {
            int c = tid + k * 512;
            if (c < DH * 22) {
                int li = c / 22, g = c - li * 22;
                int off = (i0 - 10 + li) * W + (j0 - 12) + 4 * g;   // 16B aligned
                f4 yv = *(const f4*)&y[off];
                f4 xv = *(const f4*)&X[off];
                *(f4*)&Ds[li * DW + 4 * g] = yv - xv;
            }
        }
    } else {
        #pragma unroll
        for (int k = 0; k < 3; ++k) {
            int c = tid + k * 512;
            if (c < DH * 22) {
                int li = c / 22, g = c - li * 22;
                int gi = i0 - 10 + li, gj = j0 - 12 + 4 * g;
                f4 d = {0.f, 0.f, 0.f, 0.f};
                if ((unsigned)gi < H) {
                    if (gj >= 0 && gj + 3 < W) {
                        f4 yv = *(const f4*)&y[gi * W + gj];
                        f4 xv = *(const f4*)&X[gi * W + gj];
                        d = yv - xv;
                    } else {
                        #pragma unroll
                        for (int e = 0; e < 4; ++e) {
                            int gc = gj + e;
                            if ((unsigned)gc < W) d[e] = y[gi * W + gc] - X[gi * W + gc];
                        }
                    }
                }
                *(f4*)&Ds[li * DW + 4 * g] = d;
            }
        }
    }
    __syncthreads();

    // ---- S2: H[r][4g..4g+3] = hsum5(D row r); 1040 tasks = 52 rows x 20 groups ----
    // Window for out e: Ds lc (4g+2+e)..(4g+6+e); reads a,b,c f4 at 4g,4g+4,4g+8.
    #pragma unroll
    for (int k = 0; k < 3; ++k) {
        int c = tid + k * 512;
        if (c < DH * 20) {
            int r = c / 20, g = c - r * 20;
            const f4* dp = (const f4*)&Ds[r * DW + 4 * g];
            f4 a = dp[0], b = dp[1], cc = dp[2];
            float sb123 = b.y + b.z;
            float h = b.x + sb123;                 // b0+b1+b2
            f4 o;
            o.x = a.z + a.w + h;
            o.y = a.w + h + b.w;
            o.z = h + b.w + cc.x;
            o.w = sb123 + b.w + cc.x + cc.y;
            *(f4*)&Hs[r * HS + 4 * g] = o;
        }
    }
    __syncthreads();

    // ---- S3: D2 = D - vsum17(H)/Ni1, in-place f4 RMW; 180 tasks = 9 v-segs of 4 x 20 groups ----
    if (tid < 180) {
        int seg = tid / 20, g = tid - seg * 20;
        int v0 = seg * 4;
        const f4* hp = (const f4*)&Hs[v0 * HS + 4 * g];      // f4 row stride 22
        f4 r0 = hp[0], r1 = hp[22], r2 = hp[44];
        f4 s = r0 + r1 + r2;
        #pragma unroll
        for (int t = 3; t < 17; ++t) s += hp[t * 22];
        #pragma unroll
        for (int k = 0; k < 4; ++k) {
            int v = v0 + k;
            int off = (v + 8) * DW + 4 * g + 4;              // img col j0-8+4g, aligned
            f4 d2 = *(const f4*)&Ds[off];
            if (interior) {
                d2 -= s * R85;
            } else {
                int gi = i0 + v - 2;
                if ((unsigned)gi < H) {
                    int r0c = gi - 8 > 0 ? gi - 8 : 0;
                    int r1c = gi + 8 < H - 1 ? gi + 8 : H - 1;
                    float rowsN = (float)(r1c - r0c + 1);
                    #pragma unroll
                    for (int e = 0; e < 4; ++e) {
                        int gj = j0 - 8 + 4 * g + e;
                        if ((unsigned)gj < W) {
                            int c0 = gj - 2 > 0 ? gj - 2 : 0;
                            int c1 = gj + 2 < W - 1 ? gj + 2 : W - 1;
                            d2[e] -= s[e] * __builtin_amdgcn_rcpf(rowsN * (float)(c1 - c0 + 1));
                        }   // gj outside image: keep 0 (zero-padding)
                    }
                }   // gi outside image: keep 0
            }
            *(f4*)&Ds[off] = d2;
            if (k < 3) s += hp[(k + 17) * 22] - hp[k * 22];
        }
    }
    __syncthreads();

    // ---- S4: V2[w] = vsum5(D2 rows w..w+4); 320 tasks = 16 w-segs of 2 x 20 groups ----
    if (tid < 320) {
        int seg = tid / 20, g = tid - seg * 20;
        int w0 = seg * 2;
        const f4* dp = (const f4*)&Ds[(w0 + 8) * DW + 4 * g + 4];   // aligned b128
        f4 r0 = dp[0];
        f4 s = r0 + dp[23] + dp[46] + dp[69] + dp[92];
        f4* vp = (f4*)&Hs[w0 * HS + 4 * g];
        vp[0] = s;
        s += dp[115] - r0; vp[22] = s;
    }
    __syncthreads();

    // ---- S5: out = y - D2 + hsum17(V2)/Ni2; 512 tasks = 32 rows x 16 x-groups of 4 ----
    {
        int w = tid >> 4, x0 = (tid & 15) * 4;
        int gbase = (i0 + w) * W + j0 + x0;
        f4 yv = *(const f4*)&y[gbase];                       // issue global read early
        float val[20];
        const f4* vp = (const f4*)&Hs[w * HS + x0];          // V2 centers j0-8+x0 ..
        #pragma unroll
        for (int q = 0; q < 5; ++q) {
            f4 tq = vp[q];
            val[q * 4 + 0] = tq.x; val[q * 4 + 1] = tq.y;
            val[q * 4 + 2] = tq.z; val[q * 4 + 3] = tq.w;
        }
        float s = 0.f;
        #pragma unroll
        for (int c = 0; c < 17; ++c) s += val[c];
        f4 d2 = *(const f4*)&Ds[(w + 10) * DW + x0 + 12];    // img col j0+x0, aligned
        f4 o;
        if (interior) {
            o.x = yv.x - d2.x + s * R85;
            s += val[17] - val[0];
            o.y = yv.y - d2.y + s * R85;
            s += val[18] - val[1];
            o.z = yv.z - d2.z + s * R85;
            s += val[19] - val[2];
            o.w = yv.w - d2.w + s * R85;
        } else {
            int gi = i0 + w;
            int r0c = gi - 2 > 0 ? gi - 2 : 0;
            int r1c = gi + 2 < H - 1 ? gi + 2 : H - 1;
            float rowsN = (float)(r1c - r0c + 1);
            float res[4];
            #pragma unroll
            for (int e = 0; e < 4; ++e) {
                int gj = j0 + x0 + e;
                int c0 = gj - 8 > 0 ? gj - 8 : 0;
                int c1 = gj + 8 < W - 1 ? gj + 8 : W - 1;
                res[e] = s * __builtin_amdgcn_rcpf(rowsN * (float)(c1 - c0 + 1));
                if (e < 3) s += val[e + 17] - val[e];
            }
            o.x = yv.x - d2.x + res[0];
            o.y = yv.y - d2.y + res[1];
            o.z = yv.z - d2.z + res[2];
            o.w = yv.w - d2.w + res[3];
        }
        *(f4*)&out[gbase] = o;
    }
}

extern "C" void kernel_launch(void* const* d_in, const int* in_sizes, int n_in,
                              void* d_out, int out_size, void* d_ws, size_t ws_size,
                              hipStream_t stream) {
    const float* X = (const float*)d_in[0];
    const float* y = (const float*)d_in[1];
    float* out = (float*)d_out;

    dim3 blk(512, 1, 1);
    dim3 grd(W / TX, H / TY, 1);   // 32 x 64 = 2048 blocks
    guided_fused<<<grd, blk, 0, stream>>>(X, y, out);
}